// Round 11
// baseline (336.119 us; speedup 1.0000x reference)
//
#include <hip/hip_runtime.h>

// Fused GRU-vector-neuron cell, MI355X gfx950 — round 11.
// vs round 10 (242us; runtime == MFMA-floor/MfmaUtil across R4-R10 -> pipe
// utilization-bound at 16 waves/CU): raise residency to 3 blocks/CU.
//  * LDS diet to 54,272 B (= 106*512, 3 per CU):
//      - r_t stored as u16 FIXED-POINT (r in (0,1), round(r*65536)): abs err
//        2^-17 (better than before), 8704 -> 4352 B.
//      - GAP removed.
//  * Register diet to <=85/thread (512/6 waves): phase-1 weights as 2x3-frag
//    ping-pong stepper (24 regs, was 48); phase-2 single-buffered; vout
//    packed to bf16 pairs (6 regs); __launch_bounds__(512,6).
// Numerics: r/K chain split-bf16 precise as before; vout bf16 adds <=6e-3.

#define NN   100000
#define NT   16
#define NBLK (NN / NT)   // 6250, exact
#define PSZ  16384       // us per weight plane (128x128 bf16), global ws
#define FS   520         // us per fragment in LDS A-tiles (1040 B)
#define TSZ  (12 * FS)   // us per A-tile (12 frags)

typedef unsigned short us;
typedef us     us8    __attribute__((ext_vector_type(8)));
typedef __bf16 bf16x8 __attribute__((ext_vector_type(8)));
typedef float  f32x4  __attribute__((ext_vector_type(4)));

#define MFMA __builtin_amdgcn_mfma_f32_16x16x32_bf16

__device__ __forceinline__ us f2b(float f) {   // RNE, prep only
    union { float f; unsigned u; } x; x.f = f;
    return (us)((x.u + 0x7FFFu + ((x.u >> 16) & 1u)) >> 16);
}
__device__ __forceinline__ float b2f(us h) {
    union { unsigned u; float f; } x; x.u = ((unsigned)h) << 16;
    return x.f;
}
__device__ __forceinline__ us bb(float x) { return __builtin_bit_cast(us, (__bf16)x); }

// ---- prep 1: direct weights -> bf16 planes, fragment-major ----
// planes: 0 Whz | 1 Wiz | 2,3 Whr h/l | 4,5 Wir h/l | 6 Whv | 8 Wiv
__global__ void prep_weights(const float* __restrict__ Whz, const float* __restrict__ Wiz,
                             const float* __restrict__ Whr, const float* __restrict__ Wir,
                             const float* __restrict__ Whv, const float* __restrict__ Wiv,
                             us* __restrict__ ws) {
    const int mid = blockIdx.x >> 3;
    const int s = ((blockIdx.x & 7) << 8) + threadIdx.x;
    const float* W; int hp, lp;
    switch (mid) {
        case 0: W = Whz; hp = 0; lp = -1; break;
        case 1: W = Wiz; hp = 1; lp = -1; break;
        case 2: W = Whr; hp = 2; lp = 3;  break;
        case 3: W = Wir; hp = 4; lp = 5;  break;
        case 4: W = Whv; hp = 6; lp = -1; break;
        default: W = Wiv; hp = 8; lp = -1; break;
    }
    const int f = s >> 6, l = s & 63;
    const int o  = (f >> 2) * 16 + (l & 15);
    const int c0 = (f & 3) * 32 + (l >> 4) * 8;
    us8 hi, lo;
#pragma unroll
    for (int j = 0; j < 8; ++j) {
        float x = W[(c0 + j) * 128 + o];
        us h = f2b(x);
        hi[j] = h;
        lo[j] = f2b(x - b2f(h));
    }
    *(us8*)(ws + hp * PSZ + s * 8) = hi;
    if (lp >= 0) *(us8*)(ws + lp * PSZ + s * 8) = lo;
}

// ---- prep 2: composites T = A@B (fp32) -> planes, fragment-major ----
// mat 0: Whv@Wq -> p10 | 1: Wiv@Wq -> p11 | 2: Whv@Wk -> p12,13 | 3: Wiv@Wk -> p14,15
__global__ void prep_comp(const float* __restrict__ Whv, const float* __restrict__ Wiv,
                          const float* __restrict__ Wq,  const float* __restrict__ Wk,
                          us* __restrict__ ws) {
    __shared__ float arow[128];
    const int mat = blockIdx.x >> 7;
    const int c   = blockIdx.x & 127;
    const int o   = threadIdx.x;
    const float* A = (mat & 1) ? Wiv : Whv;
    const float* B = (mat & 2) ? Wk  : Wq;
    arow[o] = A[c * 128 + o];
    __syncthreads();
    float a0 = 0.f, a1 = 0.f, a2 = 0.f, a3 = 0.f;
#pragma unroll 8
    for (int k = 0; k < 128; k += 4) {
        a0 += arow[k + 0] * B[(k + 0) * 128 + o];
        a1 += arow[k + 1] * B[(k + 1) * 128 + o];
        a2 += arow[k + 2] * B[(k + 2) * 128 + o];
        a3 += arow[k + 3] * B[(k + 3) * 128 + o];
    }
    float t = (a0 + a1) + (a2 + a3);
    const int f = (o >> 4) * 4 + (c >> 5);
    const int l = (((c >> 3) & 3) << 4) + (o & 15);
    const int off = (f * 64 + l) * 8 + (c & 7);
    static const int hpt[4] = {10, 11, 12, 14};
    const int hp = hpt[mat];
    us h = f2b(t);
    ws[hp * PSZ + off] = h;
    if (mat & 2) ws[(hp + 1) * PSZ + off] = f2b(t - b2f(h));
}

// ---- fragment loaders ----
template <int P0, int P1, int P2>
__device__ __forceinline__ void loadB3P(const us* __restrict__ ws, int wbk, bf16x8* B) {
    B[0] = *(const bf16x8*)(ws + P0 * PSZ + wbk);
    B[1] = *(const bf16x8*)(ws + P1 * PSZ + wbk);
    B[2] = *(const bf16x8*)(ws + P2 * PSZ + wbk);
}
template <int P0, int P1, int P2, int P3>
__device__ __forceinline__ void loadB4P(const us* __restrict__ ws, int wbk, bf16x8* B) {
    B[0] = *(const bf16x8*)(ws + P0 * PSZ + wbk);
    B[1] = *(const bf16x8*)(ws + P1 * PSZ + wbk);
    B[2] = *(const bf16x8*)(ws + P2 * PSZ + wbk);
    B[3] = *(const bf16x8*)(ws + P3 * PSZ + wbk);
}

// phase-1 step at one kf: B = {Wz, Wr_h, Wr_l}; z plain, r precise
__device__ __forceinline__ void mm_zr_step(const us* __restrict__ Ah, const us* __restrict__ Al,
                                           const bf16x8* B, int kf, int ab,
                                           f32x4* zacc, f32x4* racc) {
#pragma unroll
    for (int m = 0; m < 3; ++m) {
        const int fo = (m * 4 + kf) * FS + ab;
        bf16x8 ah = *(const bf16x8*)(Ah + fo);
        bf16x8 al = *(const bf16x8*)(Al + fo);
        zacc[m] = MFMA(ah, B[0], zacc[m], 0, 0, 0);
        racc[m] = MFMA(ah, B[1], racc[m], 0, 0, 0);
        racc[m] = MFMA(al, B[1], racc[m], 0, 0, 0);
        racc[m] = MFMA(ah, B[2], racc[m], 0, 0, 0);
    }
}
// phase-2 step at one kf: B = {Wd_h, CQ, CK_h, CK_l}; d/q plain, k precise
__device__ __forceinline__ void p2_half(const us* __restrict__ Ah, const us* __restrict__ Al,
                                        const bf16x8* B, int kf, int ab,
                                        f32x4* dacc, f32x4* qacc, f32x4* kacc) {
#pragma unroll
    for (int m = 0; m < 3; ++m) {
        const int fo = (m * 4 + kf) * FS + ab;
        bf16x8 ah = *(const bf16x8*)(Ah + fo);
        bf16x8 al = *(const bf16x8*)(Al + fo);
        dacc[m] = MFMA(ah, B[0], dacc[m], 0, 0, 0);
        qacc[m] = MFMA(ah, B[1], qacc[m], 0, 0, 0);
        kacc[m] = MFMA(ah, B[2], kacc[m], 0, 0, 0);
        kacc[m] = MFMA(al, B[2], kacc[m], 0, 0, 0);
        kacc[m] = MFMA(ah, B[3], kacc[m], 0, 0, 0);
    }
}

__global__ __launch_bounds__(512, 6) void gru_vn_fused(
    const float* __restrict__ v, const float* __restrict__ mv,
    const float* __restrict__ bz, const float* __restrict__ br,
    const us* __restrict__ ws, float* __restrict__ out)
{
    __shared__ __align__(16) us pool[4 * TSZ];          // 49,920 B
    __shared__ __align__(16) us r_t[128 * 17];          // 4,352 B: r u16 fixp [c*17+i]

    us* const vth = pool;                  // v, later r*v (hi)
    us* const vtl = pool + TSZ;            // v, later r*v (lo)
    us* const mvh = pool + 2 * TSZ;        // m_v (hi)
    us* const mvl = pool + 3 * TSZ;        // m_v (lo)

    const int tid  = threadIdx.x;
    const int lane = tid & 63;
    const int wave = tid >> 6;
    const int arow = lane & 15;
    const int bo   = wave * 16 + arow;       // output channel
    const int rsub = (lane >> 4) * 4;        // C-frag row offset
    const int ab   = lane * 8;               // A-frag lane offset (us)
    const int wb   = wave * 2048 + lane * 8; // B-frag base in ws (us)
    const int n0   = blockIdx.x * NT;

    // ---- stage v, m_v (hi/lo): thread = (node, c8-group, v|mv) ----
    {
        const int which = tid & 1;
        const int c8    = (tid >> 1) & 15;
        const int ind   = tid >> 5;
        const float* src = (which ? mv : v) + (size_t)(n0 + ind) * 384 + c8 * 24;
        float x[24];
#pragma unroll
        for (int t = 0; t < 6; ++t) *(float4*)(x + 4 * t) = *(const float4*)(src + 4 * t);
        us* const dh = which ? mvh : vth;
        us* const dl = which ? mvl : vtl;
        const int f0  = c8 >> 2;
        const int row = ind + ((c8 & 3) << 4);
#pragma unroll
        for (int d = 0; d < 3; ++d) {
            us8 hh, ll;
#pragma unroll
            for (int j = 0; j < 8; ++j) {
                float xv = x[j * 3 + d];
                __bf16 h = (__bf16)xv;
                hh[j] = __builtin_bit_cast(us, h);
                ll[j] = __builtin_bit_cast(us, (__bf16)(xv - (float)h));
            }
            const int off = (d * 4 + f0) * FS + row * 8;
            *(us8*)(dh + off) = hh;
            *(us8*)(dl + off) = ll;
        }
    }
    const float bzv = bz[bo], brv = br[bo];
    const f32x4 Z4 = {0.f, 0.f, 0.f, 0.f};

    // ---- phase 1: z (plain) + r (precise), 2x3-frag ping-pong stepper ----
    f32x4 zacc[3] = {Z4, Z4, Z4}, racc[3] = {Z4, Z4, Z4};
    bf16x8 BB[2][3];
    loadB3P<0, 2, 3>(ws, wb, BB[0]);
    __syncthreads();                                   // B1: tiles ready
    loadB3P<0, 2, 3>(ws, wb + 512,  BB[1]);
    mm_zr_step(mvh, mvl, BB[0], 0, ab, zacc, racc);
    loadB3P<0, 2, 3>(ws, wb + 1024, BB[0]);
    mm_zr_step(mvh, mvl, BB[1], 1, ab, zacc, racc);
    loadB3P<0, 2, 3>(ws, wb + 1536, BB[1]);
    mm_zr_step(mvh, mvl, BB[0], 2, ab, zacc, racc);
    loadB3P<1, 4, 5>(ws, wb,        BB[0]);
    mm_zr_step(mvh, mvl, BB[1], 3, ab, zacc, racc);
    loadB3P<1, 4, 5>(ws, wb + 512,  BB[1]);
    mm_zr_step(vth, vtl, BB[0], 0, ab, zacc, racc);
    loadB3P<1, 4, 5>(ws, wb + 1024, BB[0]);
    mm_zr_step(vth, vtl, BB[1], 1, ab, zacc, racc);
    loadB3P<1, 4, 5>(ws, wb + 1536, BB[1]);
    mm_zr_step(vth, vtl, BB[0], 2, ab, zacc, racc);
    mm_zr_step(vth, vtl, BB[1], 3, ab, zacc, racc);

    const int vbase = (bo >> 5) * FS + (rsub + (((bo >> 3) & 3) << 4)) * 8 + (bo & 7);
    float zz[4];
    unsigned vp[6];                                    // vout packed bf16 pairs
    {
        float vtmp[12];
#pragma unroll
        for (int q = 0; q < 4; ++q) {
            float h0 = zacc[0][q], h1 = zacc[1][q], h2 = zacc[2][q];
            zz[q] = 1.f / (1.f + __expf(-(sqrtf(h0 * h0 + h1 * h1 + h2 * h2) + bzv)));
            float r0 = racc[0][q], r1 = racc[1][q], r2 = racc[2][q];
            float rr = 1.f / (1.f + __expf(-(sqrtf(r0 * r0 + r1 * r1 + r2 * r2) + brv)));
            r_t[bo * 17 + rsub + q] = (us)fminf(rr * 65536.f, 65535.f);  // u16 fixp
#pragma unroll
            for (int d = 0; d < 3; ++d) {
                int off = vbase + d * 4 * FS + q * 8;
                vtmp[q * 3 + d] = b2f(vth[off]) + b2f(vtl[off]);
            }
        }
#pragma unroll
        for (int e = 0; e < 6; ++e)
            vp[e] = ((unsigned)bb(vtmp[2 * e + 1]) << 16) | (unsigned)bb(vtmp[2 * e]);
    }
    // preload pass-A kf0 B-frags
    bf16x8 BA[4];
    loadB4P<6, 10, 12, 13>(ws, wb, BA);
    __syncthreads();                                   // B2: r_t visible; v reads done

    // ---- overwrite v tiles with r*v (hi/lo); r decoded from u16 fixp ----
#pragma unroll
    for (int it = 0; it < 2; ++it) {
        int s = tid + it * 512;
        if (s < 768) {                                 // wave-uniform guard
            int f = s >> 6, l = s & 63;
            int i = l & 15, cb = ((f & 3) << 5) + ((l >> 4) << 3);
            int off = f * FS + l * 8;
            us8 vh8 = *(const us8*)(vth + off);
            us8 vl8 = *(const us8*)(vtl + off);
            us8 oh, ol;
#pragma unroll
            for (int j = 0; j < 8; ++j) {
                float rr = (float)r_t[(cb + j) * 17 + i] * (1.f / 65536.f);
                float p = rr * (b2f(vh8[j]) + b2f(vl8[j]));
                __bf16 h = (__bf16)p;
                oh[j] = __builtin_bit_cast(us, h);
                ol[j] = __builtin_bit_cast(us, (__bf16)(p - (float)h));
            }
            *(us8*)(vth + off) = oh;
            *(us8*)(vtl + off) = ol;
        }
    }

    // ---- phase 2 pass A (mv tiles) — before B3 (disjoint tiles) ----
    f32x4 dacc[3] = {Z4, Z4, Z4}, qacc[3] = {Z4, Z4, Z4}, kacc[3] = {Z4, Z4, Z4};
    p2_half(mvh, mvl, BA, 0, ab, dacc, qacc, kacc);
#pragma unroll
    for (int kf = 1; kf < 4; ++kf) {
        loadB4P<6, 10, 12, 13>(ws, wb + kf * 512, BA);
        p2_half(mvh, mvl, BA, kf, ab, dacc, qacc, kacc);
    }
    __syncthreads();                                   // B3: rv visible

    // ---- phase 2 pass B (rv tiles) ----
#pragma unroll
    for (int kf = 0; kf < 4; ++kf) {
        loadB4P<8, 11, 14, 15>(ws, wb + kf * 512, BA);
        p2_half(vth, vtl, BA, kf, ab, dacc, qacc, kacc);
    }

    // ---- vn-leaky + gate + store ----
#pragma unroll
    for (int q = 0; q < 4; ++q) {
        const int i = rsub + q;
        float q0 = qacc[0][q], q1 = qacc[1][q], q2 = qacc[2][q];
        float k0 = kacc[0][q], k1 = kacc[1][q], k2 = kacc[2][q];
        float inner = fminf(q0 * k0 + q1 * k1 + q2 * k2, 0.f);
        float kn = sqrtf(k0 * k0 + k1 * k1 + k2 * k2) + 1e-7f;
        float s = inner / (kn * kn);
        float z = zz[q];
        float dv0 = 0.3f * dacc[0][q] + 0.7f * (q0 - s * k0);
        float dv1 = 0.3f * dacc[1][q] + 0.7f * (q1 - s * k1);
        float dv2 = 0.3f * dacc[2][q] + 0.7f * (q2 - s * k2);
        // unpack vout (e = q*3+d; constants after unroll)
        float v0 = b2f((us)((q * 3 + 0) & 1 ? vp[(q * 3 + 0) >> 1] >> 16 : vp[(q * 3 + 0) >> 1] & 0xffffu));
        float v1 = b2f((us)((q * 3 + 1) & 1 ? vp[(q * 3 + 1) >> 1] >> 16 : vp[(q * 3 + 1) >> 1] & 0xffffu));
        float v2 = b2f((us)((q * 3 + 2) & 1 ? vp[(q * 3 + 2) >> 1] >> 16 : vp[(q * 3 + 2) >> 1] & 0xffffu));
        float* op = out + ((size_t)(n0 + i) * 128 + bo) * 3;
        op[0] = (1.f - z) * v0 + z * dv0;
        op[1] = (1.f - z) * v1 + z * dv1;
        op[2] = (1.f - z) * v2 + z * dv2;
    }
}

extern "C" void kernel_launch(void* const* d_in, const int* in_sizes, int n_in,
                              void* d_out, int out_size, void* d_ws, size_t ws_size,
                              hipStream_t stream) {
    (void)in_sizes; (void)n_in; (void)ws_size; (void)out_size;
    us* ws = (us*)d_ws;
    prep_weights<<<48, 256, 0, stream>>>(
        (const float*)d_in[2], (const float*)d_in[3],
        (const float*)d_in[5], (const float*)d_in[6],
        (const float*)d_in[8], (const float*)d_in[9], ws);
    prep_comp<<<512, 128, 0, stream>>>(
        (const float*)d_in[8],  (const float*)d_in[9],
        (const float*)d_in[10], (const float*)d_in[11], ws);
    gru_vn_fused<<<NBLK, 512, 0, stream>>>(
        (const float*)d_in[0], (const float*)d_in[1],
        (const float*)d_in[4], (const float*)d_in[7],
        ws, (float*)d_out);
}

// Round 12
// 237.983 us; speedup vs baseline: 1.4124x; 1.4124x over previous
//
#include <hip/hip_runtime.h>

// Fused GRU-vector-neuron cell, MI355X gfx950 — round 12.
// vs round 11 (336us REGRESSION: (512,6) forced VGPR 40 -> spill; R9+R11
// prove occupancy is not the lever — 2 blk/CU @ VGPR 64 is the operating pt).
// Pipe model fix: VALUBusy includes MFMA issue -> real VALU ~6%; co-bottleneck
// is the VMEM/L1 port (448 weight-frag loads/block) + MFMA, serialized by the
// phase structure.
//  * MERGED MV-PASS: phase1-mv (z,r) and passA (d,q,k) read the same mv
//    A-fragments -> one pass, 9 MFMAs per (kf,m) per 2 LDS reads. A-tile
//    reads 96->72/wave, one fewer load-use stall region, longer MFMA runs.
//  * rv-pass kf0 B-frags preloaded before B2 (latency under rebuild).
//  * Everything else = R10 proven config: FS 520, r_t fp32 [c*17+i],
//    __launch_bounds__(512,4), 3 barriers.
// Numerics bit-identical to R10 (absmax 0.03125).

#define NN   100000
#define NT   16
#define NBLK (NN / NT)   // 6250, exact
#define PSZ  16384       // us per weight plane (128x128 bf16), global ws
#define FS   520         // us per fragment in LDS A-tiles (1040 B)
#define TSZ  (12 * FS)   // us per A-tile (12 frags)
#define GAP  32

typedef unsigned short us;
typedef us     us8    __attribute__((ext_vector_type(8)));
typedef __bf16 bf16x8 __attribute__((ext_vector_type(8)));
typedef float  f32x4  __attribute__((ext_vector_type(4)));

#define MFMA __builtin_amdgcn_mfma_f32_16x16x32_bf16

__device__ __forceinline__ us f2b(float f) {   // RNE, prep only
    union { float f; unsigned u; } x; x.f = f;
    return (us)((x.u + 0x7FFFu + ((x.u >> 16) & 1u)) >> 16);
}
__device__ __forceinline__ float b2f(us h) {
    union { unsigned u; float f; } x; x.u = ((unsigned)h) << 16;
    return x.f;
}

// ---- prep 1: direct weights -> bf16 planes, fragment-major ----
// planes: 0 Whz | 1 Wiz | 2,3 Whr h/l | 4,5 Wir h/l | 6 Whv | 8 Wiv
__global__ void prep_weights(const float* __restrict__ Whz, const float* __restrict__ Wiz,
                             const float* __restrict__ Whr, const float* __restrict__ Wir,
                             const float* __restrict__ Whv, const float* __restrict__ Wiv,
                             us* __restrict__ ws) {
    const int mid = blockIdx.x >> 3;
    const int s = ((blockIdx.x & 7) << 8) + threadIdx.x;
    const float* W; int hp, lp;
    switch (mid) {
        case 0: W = Whz; hp = 0; lp = -1; break;
        case 1: W = Wiz; hp = 1; lp = -1; break;
        case 2: W = Whr; hp = 2; lp = 3;  break;
        case 3: W = Wir; hp = 4; lp = 5;  break;
        case 4: W = Whv; hp = 6; lp = -1; break;
        default: W = Wiv; hp = 8; lp = -1; break;
    }
    const int f = s >> 6, l = s & 63;
    const int o  = (f >> 2) * 16 + (l & 15);
    const int c0 = (f & 3) * 32 + (l >> 4) * 8;
    us8 hi, lo;
#pragma unroll
    for (int j = 0; j < 8; ++j) {
        float x = W[(c0 + j) * 128 + o];
        us h = f2b(x);
        hi[j] = h;
        lo[j] = f2b(x - b2f(h));
    }
    *(us8*)(ws + hp * PSZ + s * 8) = hi;
    if (lp >= 0) *(us8*)(ws + lp * PSZ + s * 8) = lo;
}

// ---- prep 2: composites T = A@B (fp32) -> planes, fragment-major ----
// mat 0: Whv@Wq -> p10 | 1: Wiv@Wq -> p11 | 2: Whv@Wk -> p12,13 | 3: Wiv@Wk -> p14,15
__global__ void prep_comp(const float* __restrict__ Whv, const float* __restrict__ Wiv,
                          const float* __restrict__ Wq,  const float* __restrict__ Wk,
                          us* __restrict__ ws) {
    __shared__ float arow[128];
    const int mat = blockIdx.x >> 7;
    const int c   = blockIdx.x & 127;
    const int o   = threadIdx.x;
    const float* A = (mat & 1) ? Wiv : Whv;
    const float* B = (mat & 2) ? Wk  : Wq;
    arow[o] = A[c * 128 + o];
    __syncthreads();
    float a0 = 0.f, a1 = 0.f, a2 = 0.f, a3 = 0.f;
#pragma unroll 8
    for (int k = 0; k < 128; k += 4) {
        a0 += arow[k + 0] * B[(k + 0) * 128 + o];
        a1 += arow[k + 1] * B[(k + 1) * 128 + o];
        a2 += arow[k + 2] * B[(k + 2) * 128 + o];
        a3 += arow[k + 3] * B[(k + 3) * 128 + o];
    }
    float t = (a0 + a1) + (a2 + a3);
    const int f = (o >> 4) * 4 + (c >> 5);
    const int l = (((c >> 3) & 3) << 4) + (o & 15);
    const int off = (f * 64 + l) * 8 + (c & 7);
    static const int hpt[4] = {10, 11, 12, 14};
    const int hp = hpt[mat];
    us h = f2b(t);
    ws[hp * PSZ + off] = h;
    if (mat & 2) ws[(hp + 1) * PSZ + off] = f2b(t - b2f(h));
}

// ---- fragment loaders ----
template <int P0, int P1, int P2>
__device__ __forceinline__ void loadB3P(const us* __restrict__ ws, int wbk, bf16x8* B) {
    B[0] = *(const bf16x8*)(ws + P0 * PSZ + wbk);
    B[1] = *(const bf16x8*)(ws + P1 * PSZ + wbk);
    B[2] = *(const bf16x8*)(ws + P2 * PSZ + wbk);
}
template <int P0, int P1, int P2, int P3>
__device__ __forceinline__ void loadB4P(const us* __restrict__ ws, int wbk, bf16x8* B) {
    B[0] = *(const bf16x8*)(ws + P0 * PSZ + wbk);
    B[1] = *(const bf16x8*)(ws + P1 * PSZ + wbk);
    B[2] = *(const bf16x8*)(ws + P2 * PSZ + wbk);
    B[3] = *(const bf16x8*)(ws + P3 * PSZ + wbk);
}
template <int P0, int P1, int P2, int P3, int P4, int P5, int P6>
__device__ __forceinline__ void loadB7P(const us* __restrict__ ws, int wbk, bf16x8* B) {
    B[0] = *(const bf16x8*)(ws + P0 * PSZ + wbk);
    B[1] = *(const bf16x8*)(ws + P1 * PSZ + wbk);
    B[2] = *(const bf16x8*)(ws + P2 * PSZ + wbk);
    B[3] = *(const bf16x8*)(ws + P3 * PSZ + wbk);
    B[4] = *(const bf16x8*)(ws + P4 * PSZ + wbk);
    B[5] = *(const bf16x8*)(ws + P5 * PSZ + wbk);
    B[6] = *(const bf16x8*)(ws + P6 * PSZ + wbk);
}

// merged mv-pass step at kf: B = {Whz, Whr_h, Whr_l, Whv, CQ, CK_h, CK_l}
// z plain, r precise, d plain, q plain, k precise — 9 MFMAs per 2 LDS reads
__device__ __forceinline__ void mv_step(const us* __restrict__ Ah, const us* __restrict__ Al,
                                        const bf16x8* B, int kf, int ab,
                                        f32x4* zacc, f32x4* racc,
                                        f32x4* dacc, f32x4* qacc, f32x4* kacc) {
#pragma unroll
    for (int m = 0; m < 3; ++m) {
        const int fo = (m * 4 + kf) * FS + ab;
        bf16x8 ah = *(const bf16x8*)(Ah + fo);
        bf16x8 al = *(const bf16x8*)(Al + fo);
        zacc[m] = MFMA(ah, B[0], zacc[m], 0, 0, 0);
        racc[m] = MFMA(ah, B[1], racc[m], 0, 0, 0);
        racc[m] = MFMA(al, B[1], racc[m], 0, 0, 0);
        racc[m] = MFMA(ah, B[2], racc[m], 0, 0, 0);
        dacc[m] = MFMA(ah, B[3], dacc[m], 0, 0, 0);
        qacc[m] = MFMA(ah, B[4], qacc[m], 0, 0, 0);
        kacc[m] = MFMA(ah, B[5], kacc[m], 0, 0, 0);
        kacc[m] = MFMA(al, B[5], kacc[m], 0, 0, 0);
        kacc[m] = MFMA(ah, B[6], kacc[m], 0, 0, 0);
    }
}
// v-pass step at kf: B = {Wiz, Wir_h, Wir_l}; z plain, r precise
__device__ __forceinline__ void zr_step(const us* __restrict__ Ah, const us* __restrict__ Al,
                                        const bf16x8* B, int kf, int ab,
                                        f32x4* zacc, f32x4* racc) {
#pragma unroll
    for (int m = 0; m < 3; ++m) {
        const int fo = (m * 4 + kf) * FS + ab;
        bf16x8 ah = *(const bf16x8*)(Ah + fo);
        bf16x8 al = *(const bf16x8*)(Al + fo);
        zacc[m] = MFMA(ah, B[0], zacc[m], 0, 0, 0);
        racc[m] = MFMA(ah, B[1], racc[m], 0, 0, 0);
        racc[m] = MFMA(al, B[1], racc[m], 0, 0, 0);
        racc[m] = MFMA(ah, B[2], racc[m], 0, 0, 0);
    }
}
// rv-pass step at kf: B = {Wiv, CQi, CKi_h, CKi_l}; d/q plain, k precise
__device__ __forceinline__ void rv_step(const us* __restrict__ Ah, const us* __restrict__ Al,
                                        const bf16x8* B, int kf, int ab,
                                        f32x4* dacc, f32x4* qacc, f32x4* kacc) {
#pragma unroll
    for (int m = 0; m < 3; ++m) {
        const int fo = (m * 4 + kf) * FS + ab;
        bf16x8 ah = *(const bf16x8*)(Ah + fo);
        bf16x8 al = *(const bf16x8*)(Al + fo);
        dacc[m] = MFMA(ah, B[0], dacc[m], 0, 0, 0);
        qacc[m] = MFMA(ah, B[1], qacc[m], 0, 0, 0);
        kacc[m] = MFMA(ah, B[2], kacc[m], 0, 0, 0);
        kacc[m] = MFMA(al, B[2], kacc[m], 0, 0, 0);
        kacc[m] = MFMA(ah, B[3], kacc[m], 0, 0, 0);
    }
}

__global__ __launch_bounds__(512, 4) void gru_vn_fused(
    const float* __restrict__ v, const float* __restrict__ mv,
    const float* __restrict__ bz, const float* __restrict__ br,
    const us* __restrict__ ws, float* __restrict__ out)
{
    __shared__ __align__(16) us pool[4 * TSZ + GAP];
    __shared__ __align__(16) float r_t[128 * 17];       // r fp32, [c*17 + i]

    us* const vth = pool;                  // v, later r*v (hi)
    us* const vtl = pool + TSZ;            // v, later r*v (lo)
    us* const mvh = pool + 2 * TSZ + GAP;  // m_v (hi)
    us* const mvl = pool + 3 * TSZ + GAP;  // m_v (lo)

    const int tid  = threadIdx.x;
    const int lane = tid & 63;
    const int wave = tid >> 6;
    const int arow = lane & 15;
    const int bo   = wave * 16 + arow;       // output channel
    const int rsub = (lane >> 4) * 4;        // C-frag row offset
    const int ab   = lane * 8;               // A-frag lane offset (us)
    const int wb   = wave * 2048 + lane * 8; // B-frag base in ws (us)
    const int n0   = blockIdx.x * NT;

    // ---- stage v, m_v (hi/lo): thread = (node, c8-group, v|mv) ----
    {
        const int which = tid & 1;
        const int c8    = (tid >> 1) & 15;
        const int ind   = tid >> 5;
        const float* src = (which ? mv : v) + (size_t)(n0 + ind) * 384 + c8 * 24;
        float x[24];
#pragma unroll
        for (int t = 0; t < 6; ++t) *(float4*)(x + 4 * t) = *(const float4*)(src + 4 * t);
        us* const dh = which ? mvh : vth;
        us* const dl = which ? mvl : vtl;
        const int f0  = c8 >> 2;
        const int row = ind + ((c8 & 3) << 4);
#pragma unroll
        for (int d = 0; d < 3; ++d) {
            us8 hh, ll;
#pragma unroll
            for (int j = 0; j < 8; ++j) {
                float xv = x[j * 3 + d];
                __bf16 h = (__bf16)xv;
                hh[j] = __builtin_bit_cast(us, h);
                ll[j] = __builtin_bit_cast(us, (__bf16)(xv - (float)h));
            }
            const int off = (d * 4 + f0) * FS + row * 8;
            *(us8*)(dh + off) = hh;
            *(us8*)(dl + off) = ll;
        }
    }
    const float bzv = bz[bo], brv = br[bo];
    const f32x4 Z4 = {0.f, 0.f, 0.f, 0.f};

    // preload merged-pass kf0 B-frags (7 planes) before the barrier
    bf16x8 B7[7];
    loadB7P<0, 2, 3, 6, 10, 12, 13>(ws, wb, B7);
    __syncthreads();                                   // B1: tiles ready

    // ---- merged mv-pass: z + r + delta + Q + K (mv contributions) ----
    f32x4 zacc[3] = {Z4, Z4, Z4}, racc[3] = {Z4, Z4, Z4};
    f32x4 dacc[3] = {Z4, Z4, Z4}, qacc[3] = {Z4, Z4, Z4}, kacc[3] = {Z4, Z4, Z4};
    mv_step(mvh, mvl, B7, 0, ab, zacc, racc, dacc, qacc, kacc);
#pragma unroll
    for (int kf = 1; kf < 4; ++kf) {
        loadB7P<0, 2, 3, 6, 10, 12, 13>(ws, wb + kf * 512, B7);
        mv_step(mvh, mvl, B7, kf, ab, zacc, racc, dacc, qacc, kacc);
    }

    // ---- v-pass: z + r (v contributions) ----
#pragma unroll
    for (int kf = 0; kf < 4; ++kf) {
        bf16x8 B3[3];
        loadB3P<1, 4, 5>(ws, wb + kf * 512, B3);
        zr_step(vth, vtl, B3, kf, ab, zacc, racc);
    }

    // ---- sigmoids, r_t write, vout capture ----
    const int vbase = (bo >> 5) * FS + (rsub + (((bo >> 3) & 3) << 4)) * 8 + (bo & 7);
    float zz[4], vout[4][3];
#pragma unroll
    for (int q = 0; q < 4; ++q) {
        float h0 = zacc[0][q], h1 = zacc[1][q], h2 = zacc[2][q];
        zz[q] = 1.f / (1.f + __expf(-(sqrtf(h0 * h0 + h1 * h1 + h2 * h2) + bzv)));
        float r0 = racc[0][q], r1 = racc[1][q], r2 = racc[2][q];
        float rr = 1.f / (1.f + __expf(-(sqrtf(r0 * r0 + r1 * r1 + r2 * r2) + brv)));
        r_t[bo * 17 + rsub + q] = rr;
#pragma unroll
        for (int d = 0; d < 3; ++d) {
            int off = vbase + d * 4 * FS + q * 8;
            vout[q][d] = b2f(vth[off]) + b2f(vtl[off]);
        }
    }
    // preload rv-pass kf0 B-frags; latency hidden under rebuild
    bf16x8 B4[4];
    loadB4P<8, 11, 14, 15>(ws, wb, B4);
    __syncthreads();                                   // B2: r_t visible; v reads done

    // ---- overwrite v tiles with r*v (hi/lo) ----
#pragma unroll
    for (int it = 0; it < 2; ++it) {
        int s = tid + it * 512;
        if (s < 768) {                                 // wave-uniform guard
            int f = s >> 6, l = s & 63;
            int i = l & 15, cb = ((f & 3) << 5) + ((l >> 4) << 3);
            int off = f * FS + l * 8;
            us8 vh8 = *(const us8*)(vth + off);
            us8 vl8 = *(const us8*)(vtl + off);
            us8 oh, ol;
#pragma unroll
            for (int j = 0; j < 8; ++j) {
                float p = r_t[(cb + j) * 17 + i] * (b2f(vh8[j]) + b2f(vl8[j]));
                __bf16 h = (__bf16)p;
                oh[j] = __builtin_bit_cast(us, h);
                ol[j] = __builtin_bit_cast(us, (__bf16)(p - (float)h));
            }
            *(us8*)(vth + off) = oh;
            *(us8*)(vtl + off) = ol;
        }
    }
    __syncthreads();                                   // B3: rv visible

    // ---- rv-pass: delta + Q + K (rv contributions) ----
    rv_step(vth, vtl, B4, 0, ab, dacc, qacc, kacc);
#pragma unroll
    for (int kf = 1; kf < 4; ++kf) {
        loadB4P<8, 11, 14, 15>(ws, wb + kf * 512, B4);
        rv_step(vth, vtl, B4, kf, ab, dacc, qacc, kacc);
    }

    // ---- vn-leaky + gate + store ----
#pragma unroll
    for (int q = 0; q < 4; ++q) {
        const int i = rsub + q;
        float q0 = qacc[0][q], q1 = qacc[1][q], q2 = qacc[2][q];
        float k0 = kacc[0][q], k1 = kacc[1][q], k2 = kacc[2][q];
        float inner = fminf(q0 * k0 + q1 * k1 + q2 * k2, 0.f);
        float kn = sqrtf(k0 * k0 + k1 * k1 + k2 * k2) + 1e-7f;
        float s = inner / (kn * kn);
        float z = zz[q];
        float dv0 = 0.3f * dacc[0][q] + 0.7f * (q0 - s * k0);
        float dv1 = 0.3f * dacc[1][q] + 0.7f * (q1 - s * k1);
        float dv2 = 0.3f * dacc[2][q] + 0.7f * (q2 - s * k2);
        float* op = out + ((size_t)(n0 + i) * 128 + bo) * 3;
        op[0] = (1.f - z) * vout[q][0] + z * dv0;
        op[1] = (1.f - z) * vout[q][1] + z * dv1;
        op[2] = (1.f - z) * vout[q][2] + z * dv2;
    }
}

extern "C" void kernel_launch(void* const* d_in, const int* in_sizes, int n_in,
                              void* d_out, int out_size, void* d_ws, size_t ws_size,
                              hipStream_t stream) {
    (void)in_sizes; (void)n_in; (void)ws_size; (void)out_size;
    us* ws = (us*)d_ws;
    prep_weights<<<48, 256, 0, stream>>>(
        (const float*)d_in[2], (const float*)d_in[3],
        (const float*)d_in[5], (const float*)d_in[6],
        (const float*)d_in[8], (const float*)d_in[9], ws);
    prep_comp<<<512, 128, 0, stream>>>(
        (const float*)d_in[8],  (const float*)d_in[9],
        (const float*)d_in[10], (const float*)d_in[11], ws);
    gru_vn_fused<<<NBLK, 512, 0, stream>>>(
        (const float*)d_in[0], (const float*)d_in[1],
        (const float*)d_in[4], (const float*)d_in[7],
        ws, (float*)d_out);
}